// Round 1
// baseline (4285.991 us; speedup 1.0000x reference)
//
#include <hip/hip_runtime.h>
#include <math.h>

namespace {
constexpr int Bc = 2, Tc = 2048, Cc = 1024, Hc = 16, KVc = 4, HDc = 64, Ec = 8, Fc = 1024;
constexpr int Nc = Bc * Tc;               // 4096 tokens
constexpr int QKVD = Cc + 2 * KVc * HDc;  // 1536
constexpr int GRP = Hc / KVc;             // 4
constexpr float RBASE = 50000.0f;

// workspace layout (in floats)
constexpr size_t OFF_H    = 0;                       // 4M  (h, later h2)
constexpr size_t OFF_HC   = 4u * 1024 * 1024;        // 4M  (hc)
constexpr size_t OFF_QKV  = 8u * 1024 * 1024;        // 6M  (qkv)  -- later gv (8M, spills into OFF_Q)
constexpr size_t OFF_Q    = 14u * 1024 * 1024;       // 4M  (q rope+ln, (B,H,T,hd))
constexpr size_t OFF_K    = 18u * 1024 * 1024;       // 1M  (k, (B,KV,T,hd))
constexpr size_t OFF_V    = 19u * 1024 * 1024;       // 1M  (v)
constexpr size_t OFF_Y    = 20u * 1024 * 1024;       // 4M  (attn out, later eh)
constexpr size_t OFF_GV   = OFF_QKV;                 // 8M
constexpr size_t OFF_EH   = OFF_Y;                   // 4M
constexpr size_t OFF_COMB = 24u * 1024 * 1024;       // 32k (combine N x E)
constexpr size_t OFF_PROB = OFF_COMB + 32768;        // 32k (probs N x E)
}

// ---------------- rmsnorm (row per block, C=1024, 256 thr x 4) ----------------
__global__ __launch_bounds__(256) void k_rmsnorm(const float* __restrict__ in,
                                                 const float* __restrict__ w,
                                                 float* __restrict__ out) {
  int n = blockIdx.x;
  int tid = threadIdx.x;
  const float* row = in + (size_t)n * Cc;
  float v[4];
  float ss = 0.f;
#pragma unroll
  for (int i = 0; i < 4; i++) {
    v[i] = row[tid + i * 256];
    ss += v[i] * v[i];
  }
#pragma unroll
  for (int m = 1; m < 64; m <<= 1) ss += __shfl_xor(ss, m);
  __shared__ float red[4];
  if ((tid & 63) == 0) red[tid >> 6] = ss;
  __syncthreads();
  float tot = red[0] + red[1] + red[2] + red[3];
  float rs = rsqrtf(tot * (1.0f / Cc) + 1e-6f);
  float* orow = out + (size_t)n * Cc;
#pragma unroll
  for (int i = 0; i < 4; i++) orow[tid + i * 256] = v[i] * rs * w[tid + i * 256];
}

// ---------------- causal depthwise conv1d (k=3, left pad 2) ----------------
__global__ __launch_bounds__(256) void k_conv(const float* __restrict__ h,
                                              const float* __restrict__ cw,
                                              float* __restrict__ hc) {
  int idx = blockIdx.x * 256 + threadIdx.x;
  if (idx >= Nc * Cc) return;
  int c = idx & (Cc - 1);
  int n = idx >> 10;
  int t = n & (Tc - 1);
  float a = (t >= 2) ? h[idx - 2 * Cc] : 0.f;
  float b = (t >= 1) ? h[idx - Cc] : 0.f;
  float d = h[idx];
  hc[idx] = a * cw[c * 3 + 0] + b * cw[c * 3 + 1] + d * cw[c * 3 + 2];
}

// ---------------- generic GEMM: C[m,n] = sum_k A[m,k]*B[n,k] ----------------
// EPI 0: C = acc ; EPI 1: C = resid + acc ; EPI 2: C += rowscale[m]*acc (skip if 0)
template <int EPI>
__global__ __launch_bounds__(256) void k_gemm_bt(const float* __restrict__ A,
                                                 const float* __restrict__ Bm,
                                                 float* __restrict__ Cm,
                                                 const float* __restrict__ resid,
                                                 const float* __restrict__ rowscale,
                                                 int rsStride, int M, int N, int K) {
  constexpr int BM = 64, BN = 64, BK = 16;
  __shared__ float As[BK][BM + 4];
  __shared__ float Bs[BK][BN + 4];
  int tid = threadIdx.x;
  int tx = tid & 15, ty = tid >> 4;
  int m0 = blockIdx.y * BM, n0 = blockIdx.x * BN;
  int kcol = tid & 15;
  int arow = (tid >> 4) * 4;
  float acc[4][4] = {};
  for (int k0 = 0; k0 < K; k0 += BK) {
#pragma unroll
    for (int i = 0; i < 4; i++)
      As[kcol][arow + i] = A[(size_t)(m0 + arow + i) * K + k0 + kcol];
#pragma unroll
    for (int i = 0; i < 4; i++)
      Bs[kcol][arow + i] = Bm[(size_t)(n0 + arow + i) * K + k0 + kcol];
    __syncthreads();
#pragma unroll
    for (int kk = 0; kk < BK; kk++) {
      float4 a4 = *(const float4*)&As[kk][ty * 4];
      float4 b4 = *(const float4*)&Bs[kk][tx * 4];
      float av[4] = {a4.x, a4.y, a4.z, a4.w};
      float bv[4] = {b4.x, b4.y, b4.z, b4.w};
#pragma unroll
      for (int i = 0; i < 4; i++)
#pragma unroll
        for (int j = 0; j < 4; j++) acc[i][j] += av[i] * bv[j];
    }
    __syncthreads();
  }
  if (EPI == 2) {
    float s = rowscale ? 0.f : 0.f;  // placate
  }
#pragma unroll
  for (int i = 0; i < 4; i++) {
    int m = m0 + ty * 4 + i;
    float s = 0.f;
    if (EPI == 2) s = rowscale[(size_t)m * rsStride];
#pragma unroll
    for (int j = 0; j < 4; j++) {
      int n = n0 + tx * 4 + j;
      size_t off = (size_t)m * N + n;
      if (EPI == 0) {
        Cm[off] = acc[i][j];
      } else if (EPI == 1) {
        Cm[off] = resid[off] + acc[i][j];
      } else {
        if (s != 0.f) Cm[off] += s * acc[i][j];
      }
    }
  }
}

// ---------------- RoPE + layernorm helper (wave of 64 = one head row) ----------------
__device__ __forceinline__ float rope_ln(float q, int lane, int t, float scale) {
  int j = lane & 31;
  float invf = powf(RBASE, -(float)j * (1.0f / 32.0f));
  float ang = (float)t * invf;
  float s, c;
  sincosf(ang, &s, &c);
  float p = __shfl_xor(q, 32);
  float rot = (lane < 32) ? -p : p;
  float qr = q * c + rot * s;
  float sum = qr, sq = qr * qr;
#pragma unroll
  for (int m = 1; m < 64; m <<= 1) {
    sum += __shfl_xor(sum, m);
    sq += __shfl_xor(sq, m);
  }
  float mean = sum * (1.0f / 64.0f);
  float var = sq * (1.0f / 64.0f) - mean * mean;
  return (qr - mean) * rsqrtf(var + 1e-5f) * scale;
}

__global__ __launch_bounds__(256) void k_ropeln_q(const float* __restrict__ qkv,
                                                  float* __restrict__ qout) {
  int gw = (blockIdx.x * 256 + threadIdx.x) >> 6;
  int lane = threadIdx.x & 63;
  if (gw >= Nc * Hc) return;
  int h = gw & (Hc - 1);
  int n = gw / Hc;
  int t = n & (Tc - 1);
  int b = n / Tc;
  float q = qkv[(size_t)n * QKVD + h * HDc + lane];
  float o = rope_ln(q, lane, t, 0.125f);  // fold 1/sqrt(hd)
  qout[(((size_t)(b * Hc + h)) * Tc + t) * HDc + lane] = o;
}

__global__ __launch_bounds__(256) void k_ropeln_kv(const float* __restrict__ qkv,
                                                   float* __restrict__ kout,
                                                   float* __restrict__ vout) {
  int gw = (blockIdx.x * 256 + threadIdx.x) >> 6;
  int lane = threadIdx.x & 63;
  if (gw >= Nc * KVc) return;
  int kv = gw & (KVc - 1);
  int n = gw / KVc;
  int t = n & (Tc - 1);
  int b = n / Tc;
  size_t base = (size_t)n * QKVD + Cc + kv * HDc;
  float kval = qkv[base + lane];
  float vval = qkv[base + KVc * HDc + lane];
  float o = rope_ln(kval, lane, t, 1.0f);
  size_t ob = (((size_t)(b * KVc + kv)) * Tc + t) * HDc + lane;
  kout[ob] = o;
  vout[ob] = vval;
}

// ---------------- flash attention (BQ=32, BK=32, block=256) ----------------
__global__ __launch_bounds__(256) void k_attn(const float* __restrict__ Q,
                                              const float* __restrict__ Kt,
                                              const float* __restrict__ Vt,
                                              float* __restrict__ Y) {
  constexpr int BQ = 32, BK = 32;
  __shared__ float Qs[BQ][HDc + 4];
  __shared__ float Ks[BK][HDc + 4];
  __shared__ float Vs[BK][HDc + 4];
  __shared__ float Ss[BQ][BK + 1];
  int tid = threadIdx.x;
  int nqb = Tc / BQ;  // 64
  int qb = blockIdx.x % nqb;
  int bh = blockIdx.x / nqb;
  int h = bh % Hc;
  int b = bh / Hc;
  int kvh = h / GRP;
  const float* qp = Q + (((size_t)(b * Hc + h)) * Tc + qb * BQ) * HDc;
  const float* kp = Kt + ((size_t)(b * KVc + kvh)) * Tc * HDc;
  const float* vp = Vt + ((size_t)(b * KVc + kvh)) * Tc * HDc;
  for (int r = tid; r < BQ * 16; r += 256) {
    int row = r >> 4, c4 = (r & 15) * 4;
    *(float4*)&Qs[row][c4] = *(const float4*)&qp[row * HDc + c4];
  }
  int row_ = tid >> 3;       // 0..31
  int cg = tid & 7;          // 0..7
  int c0 = cg * 4;
  int j0 = cg * 8;
  float m = -1e30f, l = 0.f;
  float o[8] = {};
  __syncthreads();
  for (int kt = 0; kt <= qb; kt++) {
    const float* kpt = kp + (size_t)kt * BK * HDc;
    const float* vpt = vp + (size_t)kt * BK * HDc;
    for (int r = tid; r < BK * 16; r += 256) {
      int row = r >> 4, c4 = (r & 15) * 4;
      *(float4*)&Ks[row][c4] = *(const float4*)&kpt[row * HDc + c4];
      *(float4*)&Vs[row][c4] = *(const float4*)&vpt[row * HDc + c4];
    }
    __syncthreads();
    // scores: 4 per thread
    float sc[4] = {};
#pragma unroll 4
    for (int k = 0; k < HDc; k += 4) {
      float4 q4 = *(const float4*)&Qs[row_][k];
#pragma unroll
      for (int j = 0; j < 4; j++) {
        float4 k4 = *(const float4*)&Ks[c0 + j][k];
        sc[j] += q4.x * k4.x + q4.y * k4.y + q4.z * k4.z + q4.w * k4.w;
      }
    }
    if (kt == qb) {
#pragma unroll
      for (int j = 0; j < 4; j++)
        if (c0 + j > row_) sc[j] = -1e30f;
    }
    float mx = fmaxf(fmaxf(sc[0], sc[1]), fmaxf(sc[2], sc[3]));
#pragma unroll
    for (int msk = 1; msk < 8; msk <<= 1) mx = fmaxf(mx, __shfl_xor(mx, msk));
    float mnew = fmaxf(m, mx);
    float alpha = __expf(m - mnew);
    float ps = 0.f;
#pragma unroll
    for (int j = 0; j < 4; j++) {
      float p = __expf(sc[j] - mnew);
      Ss[row_][c0 + j] = p;
      ps += p;
    }
#pragma unroll
    for (int msk = 1; msk < 8; msk <<= 1) ps += __shfl_xor(ps, msk);
    l = l * alpha + ps;
    m = mnew;
    // own-wave wrote own row of Ss; wave-lockstep makes it visible
#pragma unroll
    for (int j = 0; j < 8; j++) o[j] *= alpha;
    for (int c = 0; c < BK; c++) {
      float p = Ss[row_][c];
      float4 v0 = *(const float4*)&Vs[c][j0];
      float4 v1 = *(const float4*)&Vs[c][j0 + 4];
      o[0] += p * v0.x; o[1] += p * v0.y; o[2] += p * v0.z; o[3] += p * v0.w;
      o[4] += p * v1.x; o[5] += p * v1.y; o[6] += p * v1.z; o[7] += p * v1.w;
    }
    __syncthreads();
  }
  float inv = 1.0f / l;
  int t = qb * BQ + row_;
  size_t base = ((size_t)(b * Tc) + t) * Cc + h * HDc + j0;
#pragma unroll
  for (int j = 0; j < 8; j++) Y[base + j] = o[j] * inv;
}

// ---------------- router: logits -> softmax -> top2 -> combine ----------------
__global__ __launch_bounds__(256) void k_router(const float* __restrict__ h2,
                                                const float* __restrict__ rw,
                                                float* __restrict__ combine,
                                                float* __restrict__ probs) {
  int gw = (blockIdx.x * 256 + threadIdx.x) >> 6;
  int lane = threadIdx.x & 63;
  if (gw >= Nc) return;
  const float* row = h2 + (size_t)gw * Cc;
  float acc[Ec] = {};
  for (int k = lane; k < Cc; k += 64) {
    float hv = row[k];
#pragma unroll
    for (int e = 0; e < Ec; e++) acc[e] += hv * rw[e * Cc + k];
  }
#pragma unroll
  for (int e = 0; e < Ec; e++) {
#pragma unroll
    for (int msk = 1; msk < 64; msk <<= 1) acc[e] += __shfl_xor(acc[e], msk);
  }
  if (lane == 0) {
    float mx = acc[0];
#pragma unroll
    for (int e = 1; e < Ec; e++) mx = fmaxf(mx, acc[e]);
    float p[Ec];
    float s = 0.f;
#pragma unroll
    for (int e = 0; e < Ec; e++) {
      p[e] = expf(acc[e] - mx);
      s += p[e];
    }
    float invs = 1.0f / s;
#pragma unroll
    for (int e = 0; e < Ec; e++) {
      p[e] *= invs;
      probs[(size_t)gw * Ec + e] = p[e];
    }
    int i0 = 0;
#pragma unroll
    for (int e = 1; e < Ec; e++)
      if (p[e] > p[i0]) i0 = e;
    int i1 = (i0 == 0) ? 1 : 0;
#pragma unroll
    for (int e = 0; e < Ec; e++)
      if (e != i0 && p[e] > p[i1]) i1 = e;
    float wsum = p[i0] + p[i1];
#pragma unroll
    for (int e = 0; e < Ec; e++) combine[(size_t)gw * Ec + e] = 0.f;
    combine[(size_t)gw * Ec + i0] = p[i0] / wsum;
    combine[(size_t)gw * Ec + i1] = p[i1] / wsum;
  }
}

__global__ __launch_bounds__(256) void k_aux(const float* __restrict__ probs,
                                             float* __restrict__ outp) {
  int tid = threadIdx.x;
  int lane = tid & 63, w = tid >> 6;
  float acc[Ec] = {};
  for (int n = tid; n < Nc; n += 256) {
#pragma unroll
    for (int e = 0; e < Ec; e++) acc[e] += probs[(size_t)n * Ec + e];
  }
#pragma unroll
  for (int e = 0; e < Ec; e++) {
#pragma unroll
    for (int msk = 1; msk < 64; msk <<= 1) acc[e] += __shfl_xor(acc[e], msk);
  }
  __shared__ float red[4][Ec];
  if (lane == 0) {
#pragma unroll
    for (int e = 0; e < Ec; e++) red[w][e] = acc[e];
  }
  __syncthreads();
  if (tid == 0) {
    float aux = 0.f;
#pragma unroll
    for (int e = 0; e < Ec; e++) {
      float tot = red[0][e] + red[1][e] + red[2][e] + red[3][e];
      float avg = tot * (1.0f / Nc);
      aux += avg * avg;
    }
    outp[0] = (float)Ec * aux;
  }
}

// ---------------- SwiGLU: eh = silu(gv[:, :F]) * gv[:, F:] ----------------
__global__ __launch_bounds__(256) void k_silu(const float* __restrict__ gv,
                                              float* __restrict__ eh) {
  int idx = blockIdx.x * 256 + threadIdx.x;
  if (idx >= Nc * Fc) return;
  int n = idx >> 10;  // Fc = 1024
  int f = idx & (Fc - 1);
  float g = gv[(size_t)n * (2 * Fc) + f];
  float v = gv[(size_t)n * (2 * Fc) + Fc + f];
  eh[idx] = g / (1.0f + __expf(-g)) * v;
}

extern "C" void kernel_launch(void* const* d_in, const int* in_sizes, int n_in,
                              void* d_out, int out_size, void* d_ws, size_t ws_size,
                              hipStream_t stream) {
  const float* x      = (const float*)d_in[0];
  const float* ln1_w  = (const float*)d_in[1];
  const float* ln2_w  = (const float*)d_in[2];
  const float* conv_w = (const float*)d_in[3];
  const float* attn_w = (const float*)d_in[4];
  const float* proj_w = (const float*)d_in[5];
  const float* rout_w = (const float*)d_in[6];
  const float* ewv    = (const float*)d_in[7];
  const float* ewo    = (const float*)d_in[8];
  float* out = (float*)d_out;
  float* ws = (float*)d_ws;

  float* h    = ws + OFF_H;
  float* hc   = ws + OFF_HC;
  float* qkv  = ws + OFF_QKV;
  float* qb   = ws + OFF_Q;
  float* kb   = ws + OFF_K;
  float* vb   = ws + OFF_V;
  float* y    = ws + OFF_Y;
  float* gv   = ws + OFF_GV;
  float* eh   = ws + OFF_EH;
  float* comb = ws + OFF_COMB;
  float* prob = ws + OFF_PROB;

  // attention branch
  k_rmsnorm<<<Nc, 256, 0, stream>>>(x, ln1_w, h);
  k_conv<<<(Nc * Cc) / 256, 256, 0, stream>>>(h, conv_w, hc);
  {
    dim3 g(QKVD / 64, Nc / 64);
    k_gemm_bt<0><<<g, 256, 0, stream>>>(hc, attn_w, qkv, nullptr, nullptr, 0, Nc, QKVD, Cc);
  }
  k_ropeln_q<<<(Nc * Hc * 64) / 256, 256, 0, stream>>>(qkv, qb);
  k_ropeln_kv<<<(Nc * KVc * 64) / 256, 256, 0, stream>>>(qkv, kb, vb);
  k_attn<<<Bc * Hc * (Tc / 32), 256, 0, stream>>>(qb, kb, vb, y);
  {
    dim3 g(Cc / 64, Nc / 64);
    k_gemm_bt<1><<<g, 256, 0, stream>>>(y, proj_w, out, x, nullptr, 0, Nc, Cc, Cc);
  }
  // MoE branch
  k_rmsnorm<<<Nc, 256, 0, stream>>>(out, ln2_w, h);  // h <- h2
  k_router<<<Nc / 4, 256, 0, stream>>>(h, rout_w, comb, prob);
  k_aux<<<1, 256, 0, stream>>>(prob, out + (size_t)Nc * Cc);
  for (int e = 0; e < Ec; e++) {
    {
      dim3 g((2 * Fc) / 64, Nc / 64);
      k_gemm_bt<0><<<g, 256, 0, stream>>>(h, ewv + (size_t)e * 2 * Fc * Cc, gv,
                                          nullptr, nullptr, 0, Nc, 2 * Fc, Cc);
    }
    k_silu<<<(Nc * Fc) / 256, 256, 0, stream>>>(gv, eh);
    {
      dim3 g(Cc / 64, Nc / 64);
      k_gemm_bt<2><<<g, 256, 0, stream>>>(eh, ewo + (size_t)e * Cc * Fc, out,
                                          nullptr, comb + e, Ec, Nc, Cc, Fc);
    }
  }
}

// Round 2
// 1797.897 us; speedup vs baseline: 2.3839x; 2.3839x over previous
//
#include <hip/hip_runtime.h>
#include <math.h>

namespace {
constexpr int Bc = 2, Tc = 2048, Cc = 1024, Hc = 16, KVc = 4, HDc = 64, Ec = 8, Fc = 1024;
constexpr int Nc = Bc * Tc;               // 4096 tokens
constexpr int QKVD = Cc + 2 * KVc * HDc;  // 1536
constexpr int GRP = Hc / KVc;             // 4
constexpr float RBASE = 50000.0f;

// workspace layout (in floats) — peak usage same as round-0 (~96.3 MB, known to fit)
constexpr size_t OFF_H    = 0;                       // 4M  (h, later h2)
constexpr size_t OFF_HC   = 4u * 1024 * 1024;        // 4M  (hc)
constexpr size_t OFF_QKV  = 8u * 1024 * 1024;        // 6M  (qkv)
constexpr size_t OFF_Q    = 14u * 1024 * 1024;       // 4M  (q rope+ln, (B,H,T,hd))
constexpr size_t OFF_K    = 18u * 1024 * 1024;       // 1M  (k, (B,KV,T,hd))
constexpr size_t OFF_V    = 19u * 1024 * 1024;       // 1M  (v)
constexpr size_t OFF_Y    = 20u * 1024 * 1024;       // 4M  (attn out)
// MoE phase (attention buffers dead):
constexpr size_t OFF_GV   = 8u * 1024 * 1024;        // 8M fp32 (over qkv + q[0:2M])
constexpr size_t OFF_H2BF = 16u * 1024 * 1024;       // 2M floats = 4M bf16 (over q tail)
constexpr size_t OFF_EHBF = 18u * 1024 * 1024;       // 2M floats = 4M bf16 (over k,v)
constexpr size_t OFF_WVBF = 20u * 1024 * 1024;       // 1M floats = 2M bf16 (over y)
constexpr size_t OFF_WOBF = 21u * 1024 * 1024;       // 0.5M floats = 1M bf16
constexpr size_t OFF_COMB = 24u * 1024 * 1024;       // 32k floats (combine N x E)
constexpr size_t OFF_PROB = OFF_COMB + 32768;        // 32k floats (probs N x E)
}

typedef __attribute__((ext_vector_type(8))) short short8v;   // 8 bf16 (4 VGPRs)
typedef __attribute__((ext_vector_type(4))) float f32x4;

__device__ __forceinline__ unsigned short f2b1(float f) {
  union { float f; unsigned int u; } x;
  x.f = f;
  unsigned int r = (x.u + 0x7FFFu + ((x.u >> 16) & 1u)) >> 16;
  return (unsigned short)r;
}

// ---------------- rmsnorm (row per block, C=1024, 256 thr x 4) ----------------
__global__ __launch_bounds__(256) void k_rmsnorm(const float* __restrict__ in,
                                                 const float* __restrict__ w,
                                                 float* __restrict__ out) {
  int n = blockIdx.x;
  int tid = threadIdx.x;
  const float* row = in + (size_t)n * Cc;
  float v[4];
  float ss = 0.f;
#pragma unroll
  for (int i = 0; i < 4; i++) {
    v[i] = row[tid + i * 256];
    ss += v[i] * v[i];
  }
#pragma unroll
  for (int m = 1; m < 64; m <<= 1) ss += __shfl_xor(ss, m);
  __shared__ float red[4];
  if ((tid & 63) == 0) red[tid >> 6] = ss;
  __syncthreads();
  float tot = red[0] + red[1] + red[2] + red[3];
  float rs = rsqrtf(tot * (1.0f / Cc) + 1e-6f);
  float* orow = out + (size_t)n * Cc;
#pragma unroll
  for (int i = 0; i < 4; i++) orow[tid + i * 256] = v[i] * rs * w[tid + i * 256];
}

// ---------------- causal depthwise conv1d (k=3, left pad 2) ----------------
__global__ __launch_bounds__(256) void k_conv(const float* __restrict__ h,
                                              const float* __restrict__ cw,
                                              float* __restrict__ hc) {
  int idx = blockIdx.x * 256 + threadIdx.x;
  if (idx >= Nc * Cc) return;
  int c = idx & (Cc - 1);
  int n = idx >> 10;
  int t = n & (Tc - 1);
  float a = (t >= 2) ? h[idx - 2 * Cc] : 0.f;
  float b = (t >= 1) ? h[idx - Cc] : 0.f;
  float d = h[idx];
  hc[idx] = a * cw[c * 3 + 0] + b * cw[c * 3 + 1] + d * cw[c * 3 + 2];
}

// ---------------- fp32 GEMM (kept for qkv/proj to preserve router numerics) ----
// EPI 0: C = acc ; EPI 1: C = resid + acc
template <int EPI>
__global__ __launch_bounds__(256) void k_gemm_bt(const float* __restrict__ A,
                                                 const float* __restrict__ Bm,
                                                 float* __restrict__ Cm,
                                                 const float* __restrict__ resid,
                                                 int M, int N, int K) {
  constexpr int BM = 64, BN = 64, BK = 16;
  __shared__ float As[BK][BM + 4];
  __shared__ float Bs[BK][BN + 4];
  int tid = threadIdx.x;
  int tx = tid & 15, ty = tid >> 4;
  int m0 = blockIdx.y * BM, n0 = blockIdx.x * BN;
  int kcol = tid & 15;
  int arow = (tid >> 4) * 4;
  float acc[4][4] = {};
  for (int k0 = 0; k0 < K; k0 += BK) {
#pragma unroll
    for (int i = 0; i < 4; i++)
      As[kcol][arow + i] = A[(size_t)(m0 + arow + i) * K + k0 + kcol];
#pragma unroll
    for (int i = 0; i < 4; i++)
      Bs[kcol][arow + i] = Bm[(size_t)(n0 + arow + i) * K + k0 + kcol];
    __syncthreads();
#pragma unroll
    for (int kk = 0; kk < BK; kk++) {
      float4 a4 = *(const float4*)&As[kk][ty * 4];
      float4 b4 = *(const float4*)&Bs[kk][tx * 4];
      float av[4] = {a4.x, a4.y, a4.z, a4.w};
      float bv[4] = {b4.x, b4.y, b4.z, b4.w};
#pragma unroll
      for (int i = 0; i < 4; i++)
#pragma unroll
        for (int j = 0; j < 4; j++) acc[i][j] += av[i] * bv[j];
    }
    __syncthreads();
  }
#pragma unroll
  for (int i = 0; i < 4; i++) {
    int m = m0 + ty * 4 + i;
#pragma unroll
    for (int j = 0; j < 4; j++) {
      int n = n0 + tx * 4 + j;
      size_t off = (size_t)m * N + n;
      if (EPI == 0) Cm[off] = acc[i][j];
      else Cm[off] = resid[off] + acc[i][j];
    }
  }
}

// ---------------- bf16 MFMA GEMM (m97 structure: 128x128 tile, BK=32) --------
// C[m,n] = sum_k A[m,k]*B[n,k], A/B bf16 row-major [.,K], C fp32.
// EPI 0: C = acc ; EPI 2: C += rowscale[m*rsStride] * acc (skip if scale==0)
template <int EPI>
__global__ __launch_bounds__(256) void k_gemm_mfma(const unsigned short* __restrict__ A,
                                                   const unsigned short* __restrict__ B,
                                                   float* __restrict__ C,
                                                   const float* __restrict__ rowscale,
                                                   int rsStride, int M, int N, int K) {
  constexpr int BM = 128, BN = 128, BK = 32;
  __shared__ __align__(16) unsigned short lA[BM * BK];  // 8 KB
  __shared__ __align__(16) unsigned short lB[BN * BK];  // 8 KB
  int tid = threadIdx.x;
  int lane = tid & 63;
  int wave = tid >> 6;
  int wr = wave >> 1, wc = wave & 1;  // 2x2 wave grid, 64x64 per wave
  int m0 = blockIdx.y * BM, n0 = blockIdx.x * BN;

  f32x4 acc[4][4];
#pragma unroll
  for (int i = 0; i < 4; i++)
#pragma unroll
    for (int j = 0; j < 4; j++) acc[i][j] = (f32x4)0.f;

  int kf = (lane >> 4) * 8;  // k offset of this lane's fragment
  int rl = lane & 15;        // row/col within fragment

  for (int k0 = 0; k0 < K; k0 += BK) {
    __syncthreads();  // previous iteration's LDS reads complete
#pragma unroll
    for (int j = 0; j < 2; j++) {
      int chunk = j * 256 + tid;       // 0..511, 16B each
      int row = chunk >> 2;            // 0..127
      int cb = (chunk & 3) * 8;        // bf16 offset within row
      __builtin_amdgcn_global_load_lds(
          (const __attribute__((address_space(1))) void*)(A + (size_t)(m0 + row) * K + k0 + cb),
          (__attribute__((address_space(3))) void*)(&lA[chunk * 8]), 16, 0, 0);
    }
#pragma unroll
    for (int j = 0; j < 2; j++) {
      int chunk = j * 256 + tid;
      int row = chunk >> 2;
      int cb = (chunk & 3) * 8;
      __builtin_amdgcn_global_load_lds(
          (const __attribute__((address_space(1))) void*)(B + (size_t)(n0 + row) * K + k0 + cb),
          (__attribute__((address_space(3))) void*)(&lB[chunk * 8]), 16, 0, 0);
    }
    asm volatile("s_waitcnt vmcnt(0)" ::: "memory");
    __syncthreads();

    short8v a[4], b[4];
#pragma unroll
    for (int i = 0; i < 4; i++)
      a[i] = *(const short8v*)&lA[(wr * 64 + i * 16 + rl) * BK + kf];
#pragma unroll
    for (int j = 0; j < 4; j++)
      b[j] = *(const short8v*)&lB[(wc * 64 + j * 16 + rl) * BK + kf];
#pragma unroll
    for (int i = 0; i < 4; i++)
#pragma unroll
      for (int j = 0; j < 4; j++)
        acc[i][j] = __builtin_amdgcn_mfma_f32_16x16x32_bf16(a[i], b[j], acc[i][j], 0, 0, 0);
  }

  // epilogue: C/D layout col=lane&15, row=(lane>>4)*4+reg
  int cl = lane & 15;
  int rb = (lane >> 4) * 4;
#pragma unroll
  for (int i = 0; i < 4; i++) {
#pragma unroll
    for (int r = 0; r < 4; r++) {
      int m = m0 + wr * 64 + i * 16 + rb + r;
      float s = 1.f;
      if (EPI == 2) s = rowscale[(size_t)m * rsStride];
#pragma unroll
      for (int j = 0; j < 4; j++) {
        int n = n0 + wc * 64 + j * 16 + cl;
        size_t off = (size_t)m * N + n;
        if (EPI == 0) C[off] = acc[i][j][r];
        else if (s != 0.f) C[off] += s * acc[i][j][r];
      }
    }
  }
}

// ---------------- fp32 -> bf16 conversion (vectorized) ----------------
__global__ __launch_bounds__(256) void k_f2b(const float* __restrict__ in,
                                             unsigned short* __restrict__ outp, int n) {
  int i = (blockIdx.x * 256 + threadIdx.x) * 4;
  if (i >= n) return;
  float4 v = *(const float4*)&in[i];
  uint2 o;
  o.x = (unsigned int)f2b1(v.x) | ((unsigned int)f2b1(v.y) << 16);
  o.y = (unsigned int)f2b1(v.z) | ((unsigned int)f2b1(v.w) << 16);
  *(uint2*)&outp[i] = o;
}

// ---------------- RoPE + layernorm helper (wave of 64 = one head row) --------
__device__ __forceinline__ float rope_ln(float q, int lane, int t, float scale) {
  int j = lane & 31;
  float invf = powf(RBASE, -(float)j * (1.0f / 32.0f));
  float ang = (float)t * invf;
  float s, c;
  sincosf(ang, &s, &c);
  float p = __shfl_xor(q, 32);
  float rot = (lane < 32) ? -p : p;
  float qr = q * c + rot * s;
  float sum = qr, sq = qr * qr;
#pragma unroll
  for (int m = 1; m < 64; m <<= 1) {
    sum += __shfl_xor(sum, m);
    sq += __shfl_xor(sq, m);
  }
  float mean = sum * (1.0f / 64.0f);
  float var = sq * (1.0f / 64.0f) - mean * mean;
  return (qr - mean) * rsqrtf(var + 1e-5f) * scale;
}

__global__ __launch_bounds__(256) void k_ropeln_q(const float* __restrict__ qkv,
                                                  float* __restrict__ qout) {
  int gw = (blockIdx.x * 256 + threadIdx.x) >> 6;
  int lane = threadIdx.x & 63;
  if (gw >= Nc * Hc) return;
  int h = gw & (Hc - 1);
  int n = gw / Hc;
  int t = n & (Tc - 1);
  int b = n / Tc;
  float q = qkv[(size_t)n * QKVD + h * HDc + lane];
  float o = rope_ln(q, lane, t, 0.125f);  // fold 1/sqrt(hd)
  qout[(((size_t)(b * Hc + h)) * Tc + t) * HDc + lane] = o;
}

__global__ __launch_bounds__(256) void k_ropeln_kv(const float* __restrict__ qkv,
                                                   float* __restrict__ kout,
                                                   float* __restrict__ vout) {
  int gw = (blockIdx.x * 256 + threadIdx.x) >> 6;
  int lane = threadIdx.x & 63;
  if (gw >= Nc * KVc) return;
  int kv = gw & (KVc - 1);
  int n = gw / KVc;
  int t = n & (Tc - 1);
  int b = n / Tc;
  size_t base = (size_t)n * QKVD + Cc + kv * HDc;
  float kval = qkv[base + lane];
  float vval = qkv[base + KVc * HDc + lane];
  float o = rope_ln(kval, lane, t, 1.0f);
  size_t ob = (((size_t)(b * KVc + kv)) * Tc + t) * HDc + lane;
  kout[ob] = o;
  vout[ob] = vval;
}

// ---------------- flash attention (BQ=32, BK=32, block=256) ----------------
__global__ __launch_bounds__(256) void k_attn(const float* __restrict__ Q,
                                              const float* __restrict__ Kt,
                                              const float* __restrict__ Vt,
                                              float* __restrict__ Y) {
  constexpr int BQ = 32, BK = 32;
  __shared__ float Qs[BQ][HDc + 4];
  __shared__ float Ks[BK][HDc + 4];
  __shared__ float Vs[BK][HDc + 4];
  __shared__ float Ss[BQ][BK + 1];
  int tid = threadIdx.x;
  int nqb = Tc / BQ;  // 64
  int qb = blockIdx.x % nqb;
  int bh = blockIdx.x / nqb;
  int h = bh % Hc;
  int b = bh / Hc;
  int kvh = h / GRP;
  const float* qp = Q + (((size_t)(b * Hc + h)) * Tc + qb * BQ) * HDc;
  const float* kp = Kt + ((size_t)(b * KVc + kvh)) * Tc * HDc;
  const float* vp = Vt + ((size_t)(b * KVc + kvh)) * Tc * HDc;
  for (int r = tid; r < BQ * 16; r += 256) {
    int row = r >> 4, c4 = (r & 15) * 4;
    *(float4*)&Qs[row][c4] = *(const float4*)&qp[row * HDc + c4];
  }
  int row_ = tid >> 3;
  int cg = tid & 7;
  int c0 = cg * 4;
  int j0 = cg * 8;
  float m = -1e30f, l = 0.f;
  float o[8] = {};
  __syncthreads();
  for (int kt = 0; kt <= qb; kt++) {
    const float* kpt = kp + (size_t)kt * BK * HDc;
    const float* vpt = vp + (size_t)kt * BK * HDc;
    for (int r = tid; r < BK * 16; r += 256) {
      int row = r >> 4, c4 = (r & 15) * 4;
      *(float4*)&Ks[row][c4] = *(const float4*)&kpt[row * HDc + c4];
      *(float4*)&Vs[row][c4] = *(const float4*)&vpt[row * HDc + c4];
    }
    __syncthreads();
    float sc[4] = {};
#pragma unroll 4
    for (int k = 0; k < HDc; k += 4) {
      float4 q4 = *(const float4*)&Qs[row_][k];
#pragma unroll
      for (int j = 0; j < 4; j++) {
        float4 k4 = *(const float4*)&Ks[c0 + j][k];
        sc[j] += q4.x * k4.x + q4.y * k4.y + q4.z * k4.z + q4.w * k4.w;
      }
    }
    if (kt == qb) {
#pragma unroll
      for (int j = 0; j < 4; j++)
        if (c0 + j > row_) sc[j] = -1e30f;
    }
    float mx = fmaxf(fmaxf(sc[0], sc[1]), fmaxf(sc[2], sc[3]));
#pragma unroll
    for (int msk = 1; msk < 8; msk <<= 1) mx = fmaxf(mx, __shfl_xor(mx, msk));
    float mnew = fmaxf(m, mx);
    float alpha = __expf(m - mnew);
    float ps = 0.f;
#pragma unroll
    for (int j = 0; j < 4; j++) {
      float p = __expf(sc[j] - mnew);
      Ss[row_][c0 + j] = p;
      ps += p;
    }
#pragma unroll
    for (int msk = 1; msk < 8; msk <<= 1) ps += __shfl_xor(ps, msk);
    l = l * alpha + ps;
    m = mnew;
#pragma unroll
    for (int j = 0; j < 8; j++) o[j] *= alpha;
    for (int c = 0; c < BK; c++) {
      float p = Ss[row_][c];
      float4 v0 = *(const float4*)&Vs[c][j0];
      float4 v1 = *(const float4*)&Vs[c][j0 + 4];
      o[0] += p * v0.x; o[1] += p * v0.y; o[2] += p * v0.z; o[3] += p * v0.w;
      o[4] += p * v1.x; o[5] += p * v1.y; o[6] += p * v1.z; o[7] += p * v1.w;
    }
    __syncthreads();
  }
  float inv = 1.0f / l;
  int t = qb * BQ + row_;
  size_t base = ((size_t)(b * Tc) + t) * Cc + h * HDc + j0;
#pragma unroll
  for (int j = 0; j < 8; j++) Y[base + j] = o[j] * inv;
}

// ---------------- router: logits -> softmax -> top2 -> combine ----------------
__global__ __launch_bounds__(256) void k_router(const float* __restrict__ h2,
                                                const float* __restrict__ rw,
                                                float* __restrict__ combine,
                                                float* __restrict__ probs) {
  int gw = (blockIdx.x * 256 + threadIdx.x) >> 6;
  int lane = threadIdx.x & 63;
  if (gw >= Nc) return;
  const float* row = h2 + (size_t)gw * Cc;
  float acc[Ec] = {};
  for (int k = lane; k < Cc; k += 64) {
    float hv = row[k];
#pragma unroll
    for (int e = 0; e < Ec; e++) acc[e] += hv * rw[e * Cc + k];
  }
#pragma unroll
  for (int e = 0; e < Ec; e++) {
#pragma unroll
    for (int msk = 1; msk < 64; msk <<= 1) acc[e] += __shfl_xor(acc[e], msk);
  }
  if (lane == 0) {
    float mx = acc[0];
#pragma unroll
    for (int e = 1; e < Ec; e++) mx = fmaxf(mx, acc[e]);
    float p[Ec];
    float s = 0.f;
#pragma unroll
    for (int e = 0; e < Ec; e++) {
      p[e] = expf(acc[e] - mx);
      s += p[e];
    }
    float invs = 1.0f / s;
#pragma unroll
    for (int e = 0; e < Ec; e++) {
      p[e] *= invs;
      probs[(size_t)gw * Ec + e] = p[e];
    }
    int i0 = 0;
#pragma unroll
    for (int e = 1; e < Ec; e++)
      if (p[e] > p[i0]) i0 = e;
    int i1 = (i0 == 0) ? 1 : 0;
#pragma unroll
    for (int e = 0; e < Ec; e++)
      if (e != i0 && p[e] > p[i1]) i1 = e;
    float wsum = p[i0] + p[i1];
#pragma unroll
    for (int e = 0; e < Ec; e++) combine[(size_t)gw * Ec + e] = 0.f;
    combine[(size_t)gw * Ec + i0] = p[i0] / wsum;
    combine[(size_t)gw * Ec + i1] = p[i1] / wsum;
  }
}

__global__ __launch_bounds__(256) void k_aux(const float* __restrict__ probs,
                                             float* __restrict__ outp) {
  int tid = threadIdx.x;
  int lane = tid & 63, w = tid >> 6;
  float acc[Ec] = {};
  for (int n = tid; n < Nc; n += 256) {
#pragma unroll
    for (int e = 0; e < Ec; e++) acc[e] += probs[(size_t)n * Ec + e];
  }
#pragma unroll
  for (int e = 0; e < Ec; e++) {
#pragma unroll
    for (int msk = 1; msk < 64; msk <<= 1) acc[e] += __shfl_xor(acc[e], msk);
  }
  __shared__ float red[4][Ec];
  if (lane == 0) {
#pragma unroll
    for (int e = 0; e < Ec; e++) red[w][e] = acc[e];
  }
  __syncthreads();
  if (tid == 0) {
    float aux = 0.f;
#pragma unroll
    for (int e = 0; e < Ec; e++) {
      float tot = red[0][e] + red[1][e] + red[2][e] + red[3][e];
      float avg = tot * (1.0f / Nc);
      aux += avg * avg;
    }
    outp[0] = (float)Ec * aux;
  }
}

// ---------------- SwiGLU -> bf16: eh = silu(gv[:, :F]) * gv[:, F:] ----------------
__global__ __launch_bounds__(256) void k_silu_bf(const float* __restrict__ gv,
                                                 unsigned short* __restrict__ eh) {
  int idx = blockIdx.x * 256 + threadIdx.x;
  if (idx >= Nc * Fc) return;
  int n = idx >> 10;  // Fc = 1024
  int f = idx & (Fc - 1);
  float g = gv[(size_t)n * (2 * Fc) + f];
  float v = gv[(size_t)n * (2 * Fc) + Fc + f];
  eh[idx] = f2b1(g / (1.0f + __expf(-g)) * v);
}

extern "C" void kernel_launch(void* const* d_in, const int* in_sizes, int n_in,
                              void* d_out, int out_size, void* d_ws, size_t ws_size,
                              hipStream_t stream) {
  const float* x      = (const float*)d_in[0];
  const float* ln1_w  = (const float*)d_in[1];
  const float* ln2_w  = (const float*)d_in[2];
  const float* conv_w = (const float*)d_in[3];
  const float* attn_w = (const float*)d_in[4];
  const float* proj_w = (const float*)d_in[5];
  const float* rout_w = (const float*)d_in[6];
  const float* ewv    = (const float*)d_in[7];
  const float* ewo    = (const float*)d_in[8];
  float* out = (float*)d_out;
  float* ws = (float*)d_ws;

  float* h    = ws + OFF_H;
  float* hc   = ws + OFF_HC;
  float* qkv  = ws + OFF_QKV;
  float* qb   = ws + OFF_Q;
  float* kb   = ws + OFF_K;
  float* vb   = ws + OFF_V;
  float* y    = ws + OFF_Y;
  float* gv   = ws + OFF_GV;
  float* comb = ws + OFF_COMB;
  float* prob = ws + OFF_PROB;
  unsigned short* h2bf = (unsigned short*)(ws + OFF_H2BF);
  unsigned short* ehbf = (unsigned short*)(ws + OFF_EHBF);
  unsigned short* wvbf = (unsigned short*)(ws + OFF_WVBF);
  unsigned short* wobf = (unsigned short*)(ws + OFF_WOBF);

  // attention branch (fp32 — keeps router logits bit-identical to passing run)
  k_rmsnorm<<<Nc, 256, 0, stream>>>(x, ln1_w, h);
  k_conv<<<(Nc * Cc) / 256, 256, 0, stream>>>(h, conv_w, hc);
  {
    dim3 g(QKVD / 64, Nc / 64);
    k_gemm_bt<0><<<g, 256, 0, stream>>>(hc, attn_w, qkv, nullptr, Nc, QKVD, Cc);
  }
  k_ropeln_q<<<(Nc * Hc * 64) / 256, 256, 0, stream>>>(qkv, qb);
  k_ropeln_kv<<<(Nc * KVc * 64) / 256, 256, 0, stream>>>(qkv, kb, vb);
  k_attn<<<Bc * Hc * (Tc / 32), 256, 0, stream>>>(qb, kb, vb, y);
  {
    dim3 g(Cc / 64, Nc / 64);
    k_gemm_bt<1><<<g, 256, 0, stream>>>(y, proj_w, out, x, Nc, Cc, Cc);
  }
  // MoE branch: router fp32, expert GEMMs bf16 MFMA
  k_rmsnorm<<<Nc, 256, 0, stream>>>(out, ln2_w, h);  // h <- h2
  k_f2b<<<(Nc * Cc / 4) / 256, 256, 0, stream>>>(h, h2bf, Nc * Cc);
  k_router<<<Nc / 4, 256, 0, stream>>>(h, rout_w, comb, prob);
  k_aux<<<1, 256, 0, stream>>>(prob, out + (size_t)Nc * Cc);
  for (int e = 0; e < Ec; e++) {
    k_f2b<<<(2 * Fc * Cc / 4) / 256, 256, 0, stream>>>(ewv + (size_t)e * 2 * Fc * Cc, wvbf,
                                                       2 * Fc * Cc);
    {
      dim3 g((2 * Fc) / 128, Nc / 128);
      k_gemm_mfma<0><<<g, 256, 0, stream>>>(h2bf, wvbf, gv, nullptr, 0, Nc, 2 * Fc, Cc);
    }
    k_silu_bf<<<(Nc * Fc) / 256, 256, 0, stream>>>(gv, ehbf);
    k_f2b<<<(Cc * Fc / 4) / 256, 256, 0, stream>>>(ewo + (size_t)e * Cc * Fc, wobf, Cc * Fc);
    {
      dim3 g(Cc / 128, Nc / 128);
      k_gemm_mfma<2><<<g, 256, 0, stream>>>(ehbf, wobf, out, comb + e, Ec, Nc, Cc, Fc);
    }
  }
}

// Round 4
// 1183.589 us; speedup vs baseline: 3.6212x; 1.5190x over previous
//
#include <hip/hip_runtime.h>
#include <math.h>

namespace {
constexpr int Bc = 2, Tc = 2048, Cc = 1024, Hc = 16, KVc = 4, HDc = 64, Ec = 8, Fc = 1024;
constexpr int Nc = Bc * Tc;               // 4096 tokens
constexpr int QKVD = Cc + 2 * KVc * HDc;  // 1536
constexpr int GRP = Hc / KVc;             // 4
constexpr float RBASE = 50000.0f;

// workspace layout (in floats) — peak usage same as round-0 (~96.3 MB, known to fit)
constexpr size_t OFF_H    = 0;                       // 4M  (h, later h2)
constexpr size_t OFF_HC   = 4u * 1024 * 1024;        // 4M  (hc)
constexpr size_t OFF_QKV  = 8u * 1024 * 1024;        // 6M  (qkv)
constexpr size_t OFF_Q    = 14u * 1024 * 1024;       // 4M  (q rope+ln, (B,H,T,hd))
constexpr size_t OFF_K    = 18u * 1024 * 1024;       // 1M  (k, (B,KV,T,hd))
constexpr size_t OFF_V    = 19u * 1024 * 1024;       // 1M  (v)
constexpr size_t OFF_Y    = 20u * 1024 * 1024;       // 4M  (attn out)
// MoE phase (attention buffers dead):
constexpr size_t OFF_GV   = 8u * 1024 * 1024;        // 8M fp32
constexpr size_t OFF_H2BF = 16u * 1024 * 1024;       // 2M floats = 4M bf16
constexpr size_t OFF_EHBF = 18u * 1024 * 1024;       // 2M floats = 4M bf16
constexpr size_t OFF_WVBF = 20u * 1024 * 1024;       // 1M floats = 2M bf16
constexpr size_t OFF_WOBF = 21u * 1024 * 1024;       // 0.5M floats = 1M bf16
constexpr size_t OFF_COMB = 24u * 1024 * 1024;       // 32k floats
constexpr size_t OFF_PROB = OFF_COMB + 32768;        // 32k floats
}

typedef __attribute__((ext_vector_type(8))) short short8v;   // 8 bf16 (4 VGPRs)
typedef __attribute__((ext_vector_type(4))) short short4v;   // 4 bf16 (2 VGPRs)
typedef __attribute__((ext_vector_type(4))) float f32x4;

#define MF32(a, b, c) __builtin_amdgcn_mfma_f32_16x16x32_bf16((a), (b), (c), 0, 0, 0)

__device__ __forceinline__ unsigned short f2b1(float f) {
  union { float f; unsigned int u; } x;
  x.f = f;
  unsigned int r = (x.u + 0x7FFFu + ((x.u >> 16) & 1u)) >> 16;
  return (unsigned short)r;
}

__device__ __forceinline__ float b2f(unsigned short h) {
  union { unsigned int u; float f; } x;
  x.u = (unsigned int)h << 16;
  return x.f;
}

// split fp32 -> bf16 hi + bf16 lo (x ~= hi + lo, |err| ~ 2^-18 |x|)
__device__ __forceinline__ void split4(float4 v, short4v& hi, short4v& lo) {
  unsigned short h0 = f2b1(v.x), h1 = f2b1(v.y), h2 = f2b1(v.z), h3 = f2b1(v.w);
  hi = short4v{(short)h0, (short)h1, (short)h2, (short)h3};
  lo = short4v{(short)f2b1(v.x - b2f(h0)), (short)f2b1(v.y - b2f(h1)),
               (short)f2b1(v.z - b2f(h2)), (short)f2b1(v.w - b2f(h3))};
}

// ---------------- rmsnorm ----------------
__global__ __launch_bounds__(256) void k_rmsnorm(const float* __restrict__ in,
                                                 const float* __restrict__ w,
                                                 float* __restrict__ out) {
  int n = blockIdx.x;
  int tid = threadIdx.x;
  const float* row = in + (size_t)n * Cc;
  float v[4];
  float ss = 0.f;
#pragma unroll
  for (int i = 0; i < 4; i++) {
    v[i] = row[tid + i * 256];
    ss += v[i] * v[i];
  }
#pragma unroll
  for (int m = 1; m < 64; m <<= 1) ss += __shfl_xor(ss, m);
  __shared__ float red[4];
  if ((tid & 63) == 0) red[tid >> 6] = ss;
  __syncthreads();
  float tot = red[0] + red[1] + red[2] + red[3];
  float rs = rsqrtf(tot * (1.0f / Cc) + 1e-6f);
  float* orow = out + (size_t)n * Cc;
#pragma unroll
  for (int i = 0; i < 4; i++) orow[tid + i * 256] = v[i] * rs * w[tid + i * 256];
}

// ---------------- causal depthwise conv1d ----------------
__global__ __launch_bounds__(256) void k_conv(const float* __restrict__ h,
                                              const float* __restrict__ cw,
                                              float* __restrict__ hc) {
  int idx = blockIdx.x * 256 + threadIdx.x;
  if (idx >= Nc * Cc) return;
  int c = idx & (Cc - 1);
  int n = idx >> 10;
  int t = n & (Tc - 1);
  float a = (t >= 2) ? h[idx - 2 * Cc] : 0.f;
  float b = (t >= 1) ? h[idx - Cc] : 0.f;
  float d = h[idx];
  hc[idx] = a * cw[c * 3 + 0] + b * cw[c * 3 + 1] + d * cw[c * 3 + 2];
}

// ---------------- fp32 GEMM (qkv/proj — preserves router numerics) ----------
template <int EPI>
__global__ __launch_bounds__(256) void k_gemm_bt(const float* __restrict__ A,
                                                 const float* __restrict__ Bm,
                                                 float* __restrict__ Cm,
                                                 const float* __restrict__ resid,
                                                 int M, int N, int K) {
  constexpr int BM = 64, BN = 64, BK = 16;
  __shared__ float As[BK][BM + 4];
  __shared__ float Bs[BK][BN + 4];
  int tid = threadIdx.x;
  int tx = tid & 15, ty = tid >> 4;
  int m0 = blockIdx.y * BM, n0 = blockIdx.x * BN;
  int kcol = tid & 15;
  int arow = (tid >> 4) * 4;
  float acc[4][4] = {};
  for (int k0 = 0; k0 < K; k0 += BK) {
#pragma unroll
    for (int i = 0; i < 4; i++)
      As[kcol][arow + i] = A[(size_t)(m0 + arow + i) * K + k0 + kcol];
#pragma unroll
    for (int i = 0; i < 4; i++)
      Bs[kcol][arow + i] = Bm[(size_t)(n0 + arow + i) * K + k0 + kcol];
    __syncthreads();
#pragma unroll
    for (int kk = 0; kk < BK; kk++) {
      float4 a4 = *(const float4*)&As[kk][ty * 4];
      float4 b4 = *(const float4*)&Bs[kk][tx * 4];
      float av[4] = {a4.x, a4.y, a4.z, a4.w};
      float bv[4] = {b4.x, b4.y, b4.z, b4.w};
#pragma unroll
      for (int i = 0; i < 4; i++)
#pragma unroll
        for (int j = 0; j < 4; j++) acc[i][j] += av[i] * bv[j];
    }
    __syncthreads();
  }
#pragma unroll
  for (int i = 0; i < 4; i++) {
    int m = m0 + ty * 4 + i;
#pragma unroll
    for (int j = 0; j < 4; j++) {
      int n = n0 + tx * 4 + j;
      size_t off = (size_t)m * N + n;
      if (EPI == 0) Cm[off] = acc[i][j];
      else Cm[off] = resid[off] + acc[i][j];
    }
  }
}

// ---------------- bf16 MFMA GEMM (m97 structure, verified r1/r2) ------------
template <int EPI>
__global__ __launch_bounds__(256) void k_gemm_mfma(const unsigned short* __restrict__ A,
                                                   const unsigned short* __restrict__ B,
                                                   float* __restrict__ C,
                                                   const float* __restrict__ rowscale,
                                                   int rsStride, int M, int N, int K) {
  constexpr int BM = 128, BN = 128, BK = 32;
  __shared__ __align__(16) unsigned short lA[BM * BK];
  __shared__ __align__(16) unsigned short lB[BN * BK];
  int tid = threadIdx.x;
  int lane = tid & 63;
  int wave = tid >> 6;
  int wr = wave >> 1, wc = wave & 1;
  int m0 = blockIdx.y * BM, n0 = blockIdx.x * BN;

  f32x4 acc[4][4];
#pragma unroll
  for (int i = 0; i < 4; i++)
#pragma unroll
    for (int j = 0; j < 4; j++) acc[i][j] = (f32x4)0.f;

  int kf = (lane >> 4) * 8;
  int rl = lane & 15;

  for (int k0 = 0; k0 < K; k0 += BK) {
    __syncthreads();
#pragma unroll
    for (int j = 0; j < 2; j++) {
      int chunk = j * 256 + tid;
      int row = chunk >> 2;
      int cb = (chunk & 3) * 8;
      __builtin_amdgcn_global_load_lds(
          (const __attribute__((address_space(1))) void*)(A + (size_t)(m0 + row) * K + k0 + cb),
          (__attribute__((address_space(3))) void*)(&lA[chunk * 8]), 16, 0, 0);
    }
#pragma unroll
    for (int j = 0; j < 2; j++) {
      int chunk = j * 256 + tid;
      int row = chunk >> 2;
      int cb = (chunk & 3) * 8;
      __builtin_amdgcn_global_load_lds(
          (const __attribute__((address_space(1))) void*)(B + (size_t)(n0 + row) * K + k0 + cb),
          (__attribute__((address_space(3))) void*)(&lB[chunk * 8]), 16, 0, 0);
    }
    asm volatile("s_waitcnt vmcnt(0)" ::: "memory");
    __syncthreads();

    short8v a[4], b[4];
#pragma unroll
    for (int i = 0; i < 4; i++)
      a[i] = *(const short8v*)&lA[(wr * 64 + i * 16 + rl) * BK + kf];
#pragma unroll
    for (int j = 0; j < 4; j++)
      b[j] = *(const short8v*)&lB[(wc * 64 + j * 16 + rl) * BK + kf];
#pragma unroll
    for (int i = 0; i < 4; i++)
#pragma unroll
      for (int j = 0; j < 4; j++)
        acc[i][j] = MF32(a[i], b[j], acc[i][j]);
  }

  int cl = lane & 15;
  int rb = (lane >> 4) * 4;
#pragma unroll
  for (int i = 0; i < 4; i++) {
#pragma unroll
    for (int r = 0; r < 4; r++) {
      int m = m0 + wr * 64 + i * 16 + rb + r;
      float s = 1.f;
      if (EPI == 2) s = rowscale[(size_t)m * rsStride];
#pragma unroll
      for (int j = 0; j < 4; j++) {
        int n = n0 + wc * 64 + j * 16 + cl;
        size_t off = (size_t)m * N + n;
        if (EPI == 0) C[off] = acc[i][j][r];
        else if (s != 0.f) C[off] += s * acc[i][j][r];
      }
    }
  }
}

// ---------------- fp32 -> bf16 conversion ----------------
__global__ __launch_bounds__(256) void k_f2b(const float* __restrict__ in,
                                             unsigned short* __restrict__ outp, int n) {
  int i = (blockIdx.x * 256 + threadIdx.x) * 4;
  if (i >= n) return;
  float4 v = *(const float4*)&in[i];
  uint2 o;
  o.x = (unsigned int)f2b1(v.x) | ((unsigned int)f2b1(v.y) << 16);
  o.y = (unsigned int)f2b1(v.z) | ((unsigned int)f2b1(v.w) << 16);
  *(uint2*)&outp[i] = o;
}

// ---------------- RoPE + layernorm ----------------
__device__ __forceinline__ float rope_ln(float q, int lane, int t, float scale) {
  int j = lane & 31;
  float invf = powf(RBASE, -(float)j * (1.0f / 32.0f));
  float ang = (float)t * invf;
  float s, c;
  sincosf(ang, &s, &c);
  float p = __shfl_xor(q, 32);
  float rot = (lane < 32) ? -p : p;
  float qr = q * c + rot * s;
  float sum = qr, sq = qr * qr;
#pragma unroll
  for (int m = 1; m < 64; m <<= 1) {
    sum += __shfl_xor(sum, m);
    sq += __shfl_xor(sq, m);
  }
  float mean = sum * (1.0f / 64.0f);
  float var = sq * (1.0f / 64.0f) - mean * mean;
  return (qr - mean) * rsqrtf(var + 1e-5f) * scale;
}

__global__ __launch_bounds__(256) void k_ropeln_q(const float* __restrict__ qkv,
                                                  float* __restrict__ qout) {
  int gw = (blockIdx.x * 256 + threadIdx.x) >> 6;
  int lane = threadIdx.x & 63;
  if (gw >= Nc * Hc) return;
  int h = gw & (Hc - 1);
  int n = gw / Hc;
  int t = n & (Tc - 1);
  int b = n / Tc;
  float q = qkv[(size_t)n * QKVD + h * HDc + lane];
  float o = rope_ln(q, lane, t, 0.125f);  // fold 1/sqrt(hd)
  qout[(((size_t)(b * Hc + h)) * Tc + t) * HDc + lane] = o;
}

__global__ __launch_bounds__(256) void k_ropeln_kv(const float* __restrict__ qkv,
                                                   float* __restrict__ kout,
                                                   float* __restrict__ vout) {
  int gw = (blockIdx.x * 256 + threadIdx.x) >> 6;
  int lane = threadIdx.x & 63;
  if (gw >= Nc * KVc) return;
  int kv = gw & (KVc - 1);
  int n = gw / KVc;
  int t = n & (Tc - 1);
  int b = n / Tc;
  size_t base = (size_t)n * QKVD + Cc + kv * HDc;
  float kval = qkv[base + lane];
  float vval = qkv[base + KVc * HDc + lane];
  float o = rope_ln(kval, lane, t, 1.0f);
  size_t ob = (((size_t)(b * KVc + kv)) * Tc + t) * HDc + lane;
  kout[ob] = o;
  vout[ob] = vval;
}

// ---------------- flash attention, bf16x3 MFMA, swapped-operand S^T ---------
// BQ=64 (4 waves x 16 q), BK=64. LDS 48KB: Q(hi/lo) 16K (aliased by P after
// frag-read), K(hi/lo) 16K, V(hi/lo, d-sliced [dg][key][16]) 16K.
#define TRD(dst, off) \
  asm volatile("ds_read_b64_tr_b16 %0, %1 offset:" off : "=v"(dst) : "v"(va))

__global__ __launch_bounds__(256, 3) void k_attn2(const float* __restrict__ Q,
                                                  const float* __restrict__ K,
                                                  const float* __restrict__ V,
                                                  float* __restrict__ Y) {
  __shared__ __align__(16) unsigned char smem[49152];
  constexpr unsigned QH = 0, QL = 8192, KH = 16384, KL = 24576, VB = 32768, PB = 0;
  int tid = threadIdx.x;
  int l = tid & 63, w = tid >> 6, g = l >> 4, q15 = l & 15;
  int qtile = blockIdx.x, hh = blockIdx.y, b = blockIdx.z;
  int kvh = hh >> 2;  // GQA
  const float* qp = Q + (((size_t)(b * Hc + hh)) * Tc + qtile * 64) * HDc;
  const float* kp = K + ((size_t)(b * KVc + kvh)) * Tc * HDc;
  const float* vp = V + ((size_t)(b * KVc + kvh)) * Tc * HDc;

  // ---- stage Q (once), XOR-swizzled rows ----
#pragma unroll
  for (int i = 0; i < 4; ++i) {
    int idx = i * 256 + tid, row = idx >> 4, c4 = (idx & 15) * 4;
    float4 v4 = *(const float4*)&qp[row * HDc + c4];
    short4v hi, lo;
    split4(v4, hi, lo);
    unsigned off = (unsigned)(row * 128 + ((c4 * 2) ^ ((row & 7) << 4)));
    *(short4v*)(smem + QH + off) = hi;
    *(short4v*)(smem + QL + off) = lo;
  }
  __syncthreads();
  unsigned qsw = (unsigned)((q15 & 7) << 4);
  unsigned qro = (unsigned)((w * 16 + q15) * 128);
  short8v qhf[2], qlf[2];
  qhf[0] = *(const short8v*)(smem + QH + qro + ((16 * g) ^ qsw));
  qhf[1] = *(const short8v*)(smem + QH + qro + ((64 + 16 * g) ^ qsw));
  qlf[0] = *(const short8v*)(smem + QL + qro + ((16 * g) ^ qsw));
  qlf[1] = *(const short8v*)(smem + QL + qro + ((64 + 16 * g) ^ qsw));

  f32x4 o[4];
#pragma unroll
  for (int dt = 0; dt < 4; dt++) o[dt] = (f32x4)0.f;
  float m = -1e30f, lsum = 0.f;
  int qloc = w * 16 + q15;

  for (int kt = 0; kt <= qtile; ++kt) {
    __syncthreads();  // prior-iter LDS reads done before overwrite
    // ---- stage K (swizzled rows) and V (d-sliced slabs) ----
    {
      const float* kg = kp + (size_t)kt * 64 * HDc;
      const float* vg = vp + (size_t)kt * 64 * HDc;
#pragma unroll
      for (int i = 0; i < 4; ++i) {
        int idx = i * 256 + tid, row = idx >> 4, c4 = (idx & 15) * 4;
        float4 kv = *(const float4*)&kg[row * HDc + c4];
        short4v khi, klo;
        split4(kv, khi, klo);
        unsigned off = (unsigned)(row * 128 + ((c4 * 2) ^ ((row & 7) << 4)));
        *(short4v*)(smem + KH + off) = khi;
        *(short4v*)(smem + KL + off) = klo;
        float4 vv = *(const float4*)&vg[row * HDc + c4];
        short4v vhi, vlo;
        split4(vv, vhi, vlo);
        unsigned vo = (unsigned)(VB + (c4 >> 4) * 2048 + row * 32 + (c4 & 15) * 2);
        *(short4v*)(smem + vo) = vhi;
        *(short4v*)(smem + vo + 8192) = vlo;
      }
    }
    __syncthreads();
    const bool diag = (kt == qtile);

    // ---- S^T = K·Q^T (3-term bf16 split), per wave: [64 keys][16 q] ----
    f32x4 sv[4];
#pragma unroll
    for (int s = 0; s < 4; ++s) {
      unsigned ro = (unsigned)((s * 16 + q15) * 128);
      short8v kh0 = *(const short8v*)(smem + KH + ro + ((16 * g) ^ qsw));
      short8v kh1 = *(const short8v*)(smem + KH + ro + ((64 + 16 * g) ^ qsw));
      short8v kl0 = *(const short8v*)(smem + KL + ro + ((16 * g) ^ qsw));
      short8v kl1 = *(const short8v*)(smem + KL + ro + ((64 + 16 * g) ^ qsw));
      f32x4 a = (f32x4)0.f;
      a = MF32(kh0, qhf[0], a);
      a = MF32(kh1, qhf[1], a);
      a = MF32(kh0, qlf[0], a);
      a = MF32(kh1, qlf[1], a);
      a = MF32(kl0, qhf[0], a);
      a = MF32(kl1, qhf[1], a);
      sv[s] = a;
    }
    // ---- causal mask + online softmax (per-q stats: 2 shfl_xor) ----
    float mx = -1e30f;
#pragma unroll
    for (int s = 0; s < 4; ++s)
#pragma unroll
      for (int r = 0; r < 4; ++r) {
        if (diag && (s * 16 + g * 4 + r) > qloc) sv[s][r] = -1e30f;
        mx = fmaxf(mx, sv[s][r]);
      }
    mx = fmaxf(mx, __shfl_xor(mx, 16));
    mx = fmaxf(mx, __shfl_xor(mx, 32));
    float mnew = fmaxf(m, mx);
    float alpha = __expf(m - mnew);
    float p[4][4];
    float ps = 0.f;
#pragma unroll
    for (int s = 0; s < 4; ++s)
#pragma unroll
      for (int r = 0; r < 4; ++r) {
        p[s][r] = __expf(sv[s][r] - mnew);
        ps += p[s][r];
      }
    ps += __shfl_xor(ps, 16);
    ps += __shfl_xor(ps, 32);
    lsum = lsum * alpha + ps;
    m = mnew;
#pragma unroll
    for (int dt = 0; dt < 4; dt++) o[dt] *= alpha;
    // ---- P -> bf16 hi/lo, bounce through per-wave LDS (packed b64) ----
#pragma unroll
    for (int s = 0; s < 4; ++s) {
      unsigned short h0 = f2b1(p[s][0]), h1 = f2b1(p[s][1]), h2 = f2b1(p[s][2]),
                     h3 = f2b1(p[s][3]);
      short4v ph = short4v{(short)h0, (short)h1, (short)h2, (short)h3};
      short4v pl = short4v{(short)f2b1(p[s][0] - b2f(h0)), (short)f2b1(p[s][1] - b2f(h1)),
                           (short)f2b1(p[s][2] - b2f(h2)), (short)f2b1(p[s][3] - b2f(h3))};
      unsigned pb = (unsigned)(PB + w * 4096 + q15 * 128 +
                               (((unsigned)(s * 32 + 8 * g)) ^ qsw));
      *(short4v*)(smem + pb) = ph;
      *(short4v*)(smem + pb + 2048) = pl;
    }
    asm volatile("" ::: "memory");  // order P writes before reads (same wave)
    // ---- O^T += V^T·P^T (3-term), V^T frags via HW transpose-read ----
#pragma unroll
    for (int u = 0; u < 2; ++u) {
      // tr_read gathers the 16 lanes' 8B chunks in lane order, then delivers
      // column (l&15) of the 4x16 row-major bf16 matrix. To read V_slab
      // column-wise (lane l gets d=l&15, elems j = keys), lanes must supply
      // the CONTIGUOUS 128B window: addr = base + (l&15)*8.  (r3 bug: *2)
      unsigned va = (unsigned)(VB + u * 1024 + g * 256 + q15 * 8);
      unsigned pq = (unsigned)(PB + w * 4096 + q15 * 128 +
                               (((unsigned)(u * 64 + 16 * g)) ^ qsw));
      short8v ph8 = *(const short8v*)(smem + pq);
      short8v pl8 = *(const short8v*)(smem + pq + 2048);
      {  // dt 0,1
        short4v a0, a1, b0, b1, c0, c1, d0, d1;
        TRD(a0, "0");
        TRD(a1, "128");
        TRD(b0, "2048");
        TRD(b1, "2176");
        TRD(c0, "8192");
        TRD(c1, "8320");
        TRD(d0, "10240");
        TRD(d1, "10368");
        asm volatile("s_waitcnt lgkmcnt(0)" ::: "memory");
        __builtin_amdgcn_sched_barrier(0);
        short8v v0h = __builtin_shufflevector(a0, a1, 0, 1, 2, 3, 4, 5, 6, 7);
        short8v v1h = __builtin_shufflevector(b0, b1, 0, 1, 2, 3, 4, 5, 6, 7);
        short8v v0l = __builtin_shufflevector(c0, c1, 0, 1, 2, 3, 4, 5, 6, 7);
        short8v v1l = __builtin_shufflevector(d0, d1, 0, 1, 2, 3, 4, 5, 6, 7);
        o[0] = MF32(v0h, ph8, o[0]);
        o[0] = MF32(v0h, pl8, o[0]);
        o[0] = MF32(v0l, ph8, o[0]);
        o[1] = MF32(v1h, ph8, o[1]);
        o[1] = MF32(v1h, pl8, o[1]);
        o[1] = MF32(v1l, ph8, o[1]);
      }
      {  // dt 2,3
        short4v a0, a1, b0, b1, c0, c1, d0, d1;
        TRD(a0, "4096");
        TRD(a1, "4224");
        TRD(b0, "6144");
        TRD(b1, "6272");
        TRD(c0, "12288");
        TRD(c1, "12416");
        TRD(d0, "14336");
        TRD(d1, "14464");
        asm volatile("s_waitcnt lgkmcnt(0)" ::: "memory");
        __builtin_amdgcn_sched_barrier(0);
        short8v v2h = __builtin_shufflevector(a0, a1, 0, 1, 2, 3, 4, 5, 6, 7);
        short8v v3h = __builtin_shufflevector(b0, b1, 0, 1, 2, 3, 4, 5, 6, 7);
        short8v v2l = __builtin_shufflevector(c0, c1, 0, 1, 2, 3, 4, 5, 6, 7);
        short8v v3l = __builtin_shufflevector(d0, d1, 0, 1, 2, 3, 4, 5, 6, 7);
        o[2] = MF32(v2h, ph8, o[2]);
        o[2] = MF32(v2h, pl8, o[2]);
        o[2] = MF32(v2l, ph8, o[2]);
        o[3] = MF32(v3h, ph8, o[3]);
        o[3] = MF32(v3h, pl8, o[3]);
        o[3] = MF32(v3l, ph8, o[3]);
      }
    }
  }
  // ---- epilogue: O^T lane holds d = dt*16 + 4g + r for token q ----
  float inv = 1.0f / lsum;
  float* yr = Y + ((size_t)(b * Tc + qtile * 64 + qloc)) * Cc + hh * 64;
#pragma unroll
  for (int dt = 0; dt < 4; dt++) {
    float4 s4 = make_float4(o[dt][0] * inv, o[dt][1] * inv, o[dt][2] * inv, o[dt][3] * inv);
    *(float4*)&yr[dt * 16 + 4 * g] = s4;
  }
}

// ---------------- router ----------------
__global__ __launch_bounds__(256) void k_router(const float* __restrict__ h2,
                                                const float* __restrict__ rw,
                                                float* __restrict__ combine,
                                                float* __restrict__ probs) {
  int gw = (blockIdx.x * 256 + threadIdx.x) >> 6;
  int lane = threadIdx.x & 63;
  if (gw >= Nc) return;
  const float* row = h2 + (size_t)gw * Cc;
  float acc[Ec] = {};
  for (int k = lane; k < Cc; k += 64) {
    float hv = row[k];
#pragma unroll
    for (int e = 0; e < Ec; e++) acc[e] += hv * rw[e * Cc + k];
  }
#pragma unroll
  for (int e = 0; e < Ec; e++) {
#pragma unroll
    for (int msk = 1; msk < 64; msk <<= 1) acc[e] += __shfl_xor(acc[e], msk);
  }
  if (lane == 0) {
    float mx = acc[0];
#pragma unroll
    for (int e = 1; e < Ec; e++) mx = fmaxf(mx, acc[e]);
    float p[Ec];
    float s = 0.f;
#pragma unroll
    for (int e = 0; e < Ec; e++) {
      p[e] = expf(acc[e] - mx);
      s += p[e];
    }
    float invs = 1.0f / s;
#pragma unroll
    for (int e = 0; e < Ec; e++) {
      p[e] *= invs;
      probs[(size_t)gw * Ec + e] = p[e];
    }
    int i0 = 0;
#pragma unroll
    for (int e = 1; e < Ec; e++)
      if (p[e] > p[i0]) i0 = e;
    int i1 = (i0 == 0) ? 1 : 0;
#pragma unroll
    for (int e = 0; e < Ec; e++)
      if (e != i0 && p[e] > p[i1]) i1 = e;
    float wsum = p[i0] + p[i1];
#pragma unroll
    for (int e = 0; e < Ec; e++) combine[(size_t)gw * Ec + e] = 0.f;
    combine[(size_t)gw * Ec + i0] = p[i0] / wsum;
    combine[(size_t)gw * Ec + i1] = p[i1] / wsum;
  }
}

__global__ __launch_bounds__(256) void k_aux(const float* __restrict__ probs,
                                             float* __restrict__ outp) {
  int tid = threadIdx.x;
  int lane = tid & 63, w = tid >> 6;
  float acc[Ec] = {};
  for (int n = tid; n < Nc; n += 256) {
#pragma unroll
    for (int e = 0; e < Ec; e++) acc[e] += probs[(size_t)n * Ec + e];
  }
#pragma unroll
  for (int e = 0; e < Ec; e++) {
#pragma unroll
    for (int msk = 1; msk < 64; msk <<= 1) acc[e] += __shfl_xor(acc[e], msk);
  }
  __shared__ float red[4][Ec];
  if (lane == 0) {
#pragma unroll
    for (int e = 0; e < Ec; e++) red[w][e] = acc[e];
  }
  __syncthreads();
  if (tid == 0) {
    float aux = 0.f;
#pragma unroll
    for (int e = 0; e < Ec; e++) {
      float tot = red[0][e] + red[1][e] + red[2][e] + red[3][e];
      float avg = tot * (1.0f / Nc);
      aux += avg * avg;
    }
    outp[0] = (float)Ec * aux;
  }
}

// ---------------- SwiGLU -> bf16 ----------------
__global__ __launch_bounds__(256) void k_silu_bf(const float* __restrict__ gv,
                                                 unsigned short* __restrict__ eh) {
  int idx = blockIdx.x * 256 + threadIdx.x;
  if (idx >= Nc * Fc) return;
  int n = idx >> 10;
  int f = idx & (Fc - 1);
  float g = gv[(size_t)n * (2 * Fc) + f];
  float v = gv[(size_t)n * (2 * Fc) + Fc + f];
  eh[idx] = f2b1(g / (1.0f + __expf(-g)) * v);
}

extern "C" void kernel_launch(void* const* d_in, const int* in_sizes, int n_in,
                              void* d_out, int out_size, void* d_ws, size_t ws_size,
                              hipStream_t stream) {
  const float* x      = (const float*)d_in[0];
  const float* ln1_w  = (const float*)d_in[1];
  const float* ln2_w  = (const float*)d_in[2];
  const float* conv_w = (const float*)d_in[3];
  const float* attn_w = (const float*)d_in[4];
  const float* proj_w = (const float*)d_in[5];
  const float* rout_w = (const float*)d_in[6];
  const float* ewv    = (const float*)d_in[7];
  const float* ewo    = (const float*)d_in[8];
  float* out = (float*)d_out;
  float* ws = (float*)d_ws;

  float* h    = ws + OFF_H;
  float* hc   = ws + OFF_HC;
  float* qkv  = ws + OFF_QKV;
  float* qb   = ws + OFF_Q;
  float* kb   = ws + OFF_K;
  float* vb   = ws + OFF_V;
  float* y    = ws + OFF_Y;
  float* gv   = ws + OFF_GV;
  float* comb = ws + OFF_COMB;
  float* prob = ws + OFF_PROB;
  unsigned short* h2bf = (unsigned short*)(ws + OFF_H2BF);
  unsigned short* ehbf = (unsigned short*)(ws + OFF_EHBF);
  unsigned short* wvbf = (unsigned short*)(ws + OFF_WVBF);
  unsigned short* wobf = (unsigned short*)(ws + OFF_WOBF);

  // attention branch
  k_rmsnorm<<<Nc, 256, 0, stream>>>(x, ln1_w, h);
  k_conv<<<(Nc * Cc) / 256, 256, 0, stream>>>(h, conv_w, hc);
  {
    dim3 g(QKVD / 64, Nc / 64);
    k_gemm_bt<0><<<g, 256, 0, stream>>>(hc, attn_w, qkv, nullptr, Nc, QKVD, Cc);
  }
  k_ropeln_q<<<(Nc * Hc * 64) / 256, 256, 0, stream>>>(qkv, qb);
  k_ropeln_kv<<<(Nc * KVc * 64) / 256, 256, 0, stream>>>(qkv, kb, vb);
  k_attn2<<<dim3(Tc / 64, Hc, Bc), 256, 0, stream>>>(qb, kb, vb, y);
  {
    dim3 g(Cc / 64, Nc / 64);
    k_gemm_bt<1><<<g, 256, 0, stream>>>(y, proj_w, out, x, Nc, Cc, Cc);
  }
  // MoE branch
  k_rmsnorm<<<Nc, 256, 0, stream>>>(out, ln2_w, h);
  k_f2b<<<(Nc * Cc / 4) / 256, 256, 0, stream>>>(h, h2bf, Nc * Cc);
  k_router<<<Nc / 4, 256, 0, stream>>>(h, rout_w, comb, prob);
  k_aux<<<1, 256, 0, stream>>>(prob, out + (size_t)Nc * Cc);
  for (int e = 0; e < Ec; e++) {
    k_f2b<<<(2 * Fc * Cc / 4) / 256, 256, 0, stream>>>(ewv + (size_t)e * 2 * Fc * Cc, wvbf,
                                                       2 * Fc * Cc);
    {
      dim3 g((2 * Fc) / 128, Nc / 128);
      k_gemm_mfma<0><<<g, 256, 0, stream>>>(h2bf, wvbf, gv, nullptr, 0, Nc, 2 * Fc, Cc);
    }
    k_silu_bf<<<(Nc * Fc) / 256, 256, 0, stream>>>(gv, ehbf);
    k_f2b<<<(Cc * Fc / 4) / 256, 256, 0, stream>>>(ewo + (size_t)e * Cc * Fc, wobf, Cc * Fc);
    {
      dim3 g(Cc / 128, Nc / 128);
      k_gemm_mfma<2><<<g, 256, 0, stream>>>(ehbf, wobf, out, comb + e, Ec, Nc, Cc, Fc);
    }
  }
}